// Round 22
// baseline (364.081 us; speedup 1.0000x reference)
//
#include <hip/hip_runtime.h>
#include <math.h>

#define NWIN 512
#define NHD  3
#define NTOK 343
#define HD   32
#define CH   96
#define DIM  56

#define XS 16.0f
#define WS 1024.0f
#define RS (1.0f/16384.0f)   // 2^-14, exact

typedef __attribute__((ext_vector_type(8))) _Float16 f16x8;
typedef __attribute__((ext_vector_type(4))) float f32x4;
typedef __attribute__((ext_vector_type(2))) _Float16 h2;

__device__ __forceinline__ unsigned short f2h_bits(float x) {
    _Float16 h = (_Float16)x;
    return __builtin_bit_cast(unsigned short, h);
}
__device__ __forceinline__ float h2f_bits(unsigned short u) {
    return (float)__builtin_bit_cast(_Float16, u);
}
__device__ __forceinline__ f32x4 mfma16h(f16x8 a, f16x8 b, f32x4 c) {
    return __builtin_amdgcn_mfma_f32_16x16x32_f16(a, b, c, 0, 0, 0);
}
__device__ __forceinline__ float shfl16_sum(float v) {  // sum over lane&15 group
    v += __shfl_xor(v, 1);
    v += __shfl_xor(v, 2);
    v += __shfl_xor(v, 4);
    v += __shfl_xor(v, 8);
    return v;
}

// w_qkv -> split-fp16 MFMA B-fragments in d_ws (110592 B).
// fid = ((((h*3+m)*2+nt)*3+ks)*2+hl); elem = fid*512 + lane*8 + e
__global__ void setup_w(const float* __restrict__ w_qkv,
                        unsigned short* __restrict__ wsb)
{
    int i = blockIdx.x * 256 + threadIdx.x;
    if (i >= 108 * 512) return;
    int e = i & 7, l = (i >> 3) & 63;
    int fid = i >> 9;
    int hl = fid & 1; int f2 = fid >> 1;
    int ks = f2 % 3; int f3 = f2 / 3;
    int nt = f3 & 1; int f4 = f3 >> 1;
    int m  = f4 % 3; int h  = f4 / 3;
    int kg  = ks * 32 + (l >> 4) * 8 + e;
    int col = m * 96 + h * 32 + nt * 16 + (l & 15);
    float w = w_qkv[kg * 288 + col] * WS;
    unsigned short hi = f2h_bits(w);
    wsb[i] = hl ? f2h_bits(w - h2f_bits(hi)) : hi;
}

// Builds scaled fp16-split A-fragments for token (clamped) from global x.
#define BUILD_AFRAG(AH, AL, XPTR)                                           \
  { _Pragma("unroll")                                                       \
    for (int ks = 0; ks < 3; ++ks) {                                        \
        float4 x0 = *(const float4*)((XPTR) + ks * 32);                     \
        float4 x1 = *(const float4*)((XPTR) + ks * 32 + 4);                 \
        union { _Float16 e[8]; f16x8 v; } th, tl;                           \
        float s[8] = {x0.x, x0.y, x0.z, x0.w, x1.x, x1.y, x1.z, x1.w};      \
        _Pragma("unroll")                                                   \
        for (int e = 0; e < 8; ++e) {                                       \
            float sv = s[e] * XS;                                           \
            unsigned short hi = f2h_bits(sv);                               \
            th.e[e] = __builtin_bit_cast(_Float16, hi);                     \
            tl.e[e] = (_Float16)(sv - h2f_bits(hi));                       \
        }                                                                   \
        AH[ks] = th.v; AL[ks] = tl.v;                                       \
    } }

// One block per (head, window), 256 threads, 4 blocks/CU (LDS pinned 38912).
// XCD swizzle: swz=(bid&7)*192+(bid>>3); h=swz%3, win=swz/3.
// Phase A (single x pass, fully unrolled 6 chunks): q,k,v MFMA; transforms;
//   qfin packed into 24 REGISTERS (qreg[6][4]); kfin->kf16c, v->v16;
//   kv-accum via MFMA.
// Phase B (barrier-free): unpack qreg -> z + qfL staging -> att MFMA -> y.
// Phase C: packed-fp16 conv.
__global__ __launch_bounds__(256, 4) void attn_kernel(
    const float* __restrict__ x, const unsigned short* __restrict__ wsb,
    const float* __restrict__ scale_param, const float* __restrict__ pos_enc,
    const float* __restrict__ dwc_w, const float* __restrict__ dwc_b,
    float* __restrict__ y)
{
    __shared__ __align__(16) unsigned short v16[352 * HD];    // 22528 B
    __shared__ __align__(16) union UU {
        struct PA { unsigned short kf16c[64 * 34]; } pa;      // 4352 B
        struct PB {
            unsigned short qfL[64 * 40];   // 5120 B
            unsigned short kvS[32 * 40];   // 2560 B
            float ksred[4][2][16];         // 512 B
        } pb;                                                 // 8192 B
        unsigned dwcP[16 * 125];                              // 8000 B
        float pad_pin_lds[4000];                              // 16000 B -> pin
    } u;
    __shared__ float ksum_s[HD];
    __shared__ float sps[HD];
    // total 38784 B (reported 38912) -> 4 blocks/CU

    const int tid = threadIdx.x, bid = blockIdx.x;
    const int swz = (bid & 7) * 192 + (bid >> 3);   // XCD-contiguous id
    const int win = swz / 3;
    const int h   = swz - win * 3;
    const int wd = win >> 6, wh = (win >> 3) & 7, ww = win & 7;
    const int wv = tid >> 6, lane = tid & 63;
    const int quad = lane >> 4, li = lane & 15;
    const int mtw = wv >> 1, ntw = wv & 1;

    if (tid < HD) {
        float sv = scale_param[tid];
        sps[tid] = (sv > 20.f) ? sv : log1pf(expf(sv));
    }
    __syncthreads();
    const float sp0 = sps[li], sp1 = sps[16 + li];

    const f16x8* wf = (const f16x8*)wsb;
    const int fbase = h * 36;
    float ksp0 = 0.f, ksp1 = 0.f;
    f32x4 kvacc = {0.f, 0.f, 0.f, 0.f};
    unsigned qreg[6][4];                 // qfin fp16 pairs, statically indexed

    // ========= Phase A: q,k,v in ONE x pass (6 chunks, full unroll) ======
    #pragma unroll
    for (int c6 = 0; c6 < 6; ++c6) {
        const int cb0 = c6 * 64;
        const int nj = (c6 < 5) ? 64 : (NTOK - 320);
        int atok = cb0 + wv * 16 + li;
        int atc = min(atok, NTOK - 1);
        int adz = atc / 49, arem = atc - adz * 49, ady = arem / 7, adx = arem - ady * 7;
        int gA = ((wd * 7 + adz) * DIM + (wh * 7 + ady)) * DIM + (ww * 7 + adx);
        const float* xr = x + (size_t)gA * CH + quad * 8;
        f16x8 ah[3], al[3];
        BUILD_AFRAG(ah, al, xr);

        f32x4 aq[2] = {{0,0,0,0},{0,0,0,0}};
        f32x4 ak[2] = {{0,0,0,0},{0,0,0,0}};
        f32x4 av[2] = {{0,0,0,0},{0,0,0,0}};
        #pragma unroll
        for (int nt = 0; nt < 2; ++nt) {
            #pragma unroll
            for (int ks = 0; ks < 3; ++ks) {
                int fq = (fbase + ((0 * 2 + nt) * 3 + ks) * 2) * 64 + lane;
                int fk = (fbase + ((1 * 2 + nt) * 3 + ks) * 2) * 64 + lane;
                int fv = (fbase + ((2 * 2 + nt) * 3 + ks) * 2) * 64 + lane;
                f16x8 bqh = wf[fq], bql = wf[fq + 64];
                f16x8 bkh = wf[fk], bkl = wf[fk + 64];
                f16x8 bvh = wf[fv];
                aq[nt] = mfma16h(ah[ks], bqh, aq[nt]);
                aq[nt] = mfma16h(ah[ks], bql, aq[nt]);
                aq[nt] = mfma16h(al[ks], bqh, aq[nt]);
                ak[nt] = mfma16h(ah[ks], bkh, ak[nt]);
                ak[nt] = mfma16h(ah[ks], bkl, ak[nt]);
                ak[nt] = mfma16h(al[ks], bkh, ak[nt]);
                av[nt] = mfma16h(ah[ks], bvh, av[nt]);
                av[nt] = mfma16h(al[ks], bvh, av[nt]);
            }
        }

        // k + q transforms in C-layout: token = cb0+wv*16+quad*4+j
        #pragma unroll
        for (int j = 0; j < 4; ++j) {
            int t16 = quad * 4 + j;
            int tok = cb0 + wv * 16 + t16;
            bool val = tok < NTOK;
            int tc = val ? tok : NTOK - 1;
            float pe0 = pos_enc[tc * HD + li];
            float pe1 = pos_enc[tc * HD + 16 + li];
            float kr0 = ak[0][j] * RS + pe0;
            float kr1 = ak[1][j] * RS + pe1;
            float kp0 = (fmaxf(kr0, 0.f) + 1e-6f) / sp0;
            float kp1 = (fmaxf(kr1, 0.f) + 1e-6f) / sp1;
            float k30 = kp0 * kp0 * kp0, k31 = kp1 * kp1 * kp1;
            float qp0 = (fmaxf(aq[0][j] * RS, 0.f) + 1e-6f) / sp0;
            float qp1 = (fmaxf(aq[1][j] * RS, 0.f) + 1e-6f) / sp1;
            float q30 = qp0 * qp0 * qp0, q31 = qp1 * qp1 * qp1;
            float n2k = fmaf(kp0, kp0, kp1 * kp1);
            float n6k = fmaf(k30, k30, k31 * k31);
            float n2q = fmaf(qp0, qp0, qp1 * qp1);
            float n6q = fmaf(q30, q30, q31 * q31);
            n2k = shfl16_sum(n2k); n6k = shfl16_sum(n6k);
            n2q = shfl16_sum(n2q); n6q = shfl16_sum(n6q);
            float sk = sqrtf(n2k / n6k), sq = sqrtf(n2q / n6q);
            float kf0 = k30 * sk, kf1 = k31 * sk;
            float qf0 = q30 * sq, qf1 = q31 * sq;
            qreg[c6][j] = (unsigned)f2h_bits(qf0) | ((unsigned)f2h_bits(qf1) << 16);
            int tl = wv * 16 + t16;
            if (val) {
                ksp0 += kf0; ksp1 += kf1;
                u.pa.kf16c[tl * 34 + li]      = f2h_bits(kf0);
                u.pa.kf16c[tl * 34 + 16 + li] = f2h_bits(kf1);
                v16[tok * HD + li]      = f2h_bits(av[0][j] * RS);
                v16[tok * HD + 16 + li] = f2h_bits(av[1][j] * RS);
            } else {
                u.pa.kf16c[tl * 34 + li]      = 0;
                u.pa.kf16c[tl * 34 + 16 + li] = 0;
                if (tok < 352) {
                    v16[tok * HD + li]      = 0;
                    v16[tok * HD + 16 + li] = 0;
                }
            }
        }
        __syncthreads();   // kf16c/v16 ready

        const int nsteps = (nj + 31) >> 5;
        for (int s = 0; s < nsteps; ++s) {
            union { unsigned short u16a[8]; f16x8 v; } a8, b8;
            #pragma unroll
            for (int e = 0; e < 8; ++e) {
                int row = s * 32 + quad * 8 + e;
                a8.u16a[e] = u.pa.kf16c[row * 34 + mtw * 16 + li];
                b8.u16a[e] = v16[(cb0 + row) * HD + ntw * 16 + li];
            }
            kvacc = mfma16h(a8.v, b8.v, kvacc);
        }
        __syncthreads();   // kf16c reads done before next chunk's writes
    }

    // ===== interphase: ksum reduce + kv C-frags -> fp16 kvS B-frag LDS ====
    ksp0 += __shfl_xor(ksp0, 16); ksp0 += __shfl_xor(ksp0, 32);
    ksp1 += __shfl_xor(ksp1, 16); ksp1 += __shfl_xor(ksp1, 32);
    if (quad == 0) { u.pb.ksred[wv][0][li] = ksp0; u.pb.ksred[wv][1][li] = ksp1; }
    #pragma unroll
    for (int j = 0; j < 4; ++j)
        u.pb.kvS[(ntw * 16 + li) * 40 + mtw * 16 + quad * 4 + j] = f2h_bits(kvacc[j]);
    __syncthreads();
    if (tid < HD) {
        ksum_s[tid] = u.pb.ksred[0][tid >> 4][tid & 15] + u.pb.ksred[1][tid >> 4][tid & 15]
                    + u.pb.ksred[2][tid >> 4][tid & 15] + u.pb.ksred[3][tid >> 4][tid & 15];
    }
    __syncthreads();

    // == Phase B (barrier-free): qreg -> z, qfL staging, att MFMA, store y ==
    const float ks0 = ksum_s[li], ks1 = ksum_s[16 + li];
    f16x8 bk0 = *(const f16x8*)&u.pb.kvS[li * 40 + quad * 8];
    f16x8 bk1 = *(const f16x8*)&u.pb.kvS[(16 + li) * 40 + quad * 8];
    #pragma unroll
    for (int c6 = 0; c6 < 6; ++c6) {
        const int cb0 = c6 * 64;
        float zq[4];
        #pragma unroll
        for (int j = 0; j < 4; ++j) {
            unsigned qp = qreg[c6][j];
            float qf0 = h2f_bits((unsigned short)(qp & 0xffff));
            float qf1 = h2f_bits((unsigned short)(qp >> 16));
            float zp = shfl16_sum(fmaf(qf0, ks0, qf1 * ks1));
            zq[j] = 1.f / (zp + 1e-6f);
            int tl = wv * 16 + quad * 4 + j;
            u.pb.qfL[tl * 40 + li]      = (unsigned short)(qp & 0xffff);
            u.pb.qfL[tl * 40 + 16 + li] = (unsigned short)(qp >> 16);
        }
        // same-wave write->read (rows wv*16..+15 are wave-private)
        f16x8 aqf = *(const f16x8*)&u.pb.qfL[(wv * 16 + li) * 40 + quad * 8];
        f32x4 at0 = {0.f, 0.f, 0.f, 0.f}, at1 = {0.f, 0.f, 0.f, 0.f};
        at0 = mfma16h(aqf, bk0, at0);
        at1 = mfma16h(aqf, bk1, at1);

        #pragma unroll
        for (int j = 0; j < 4; ++j) {
            int tok = cb0 + wv * 16 + quad * 4 + j;
            if (tok < NTOK) {
                int dz = tok / 49, rem = tok - dz * 49, dy = rem / 7, dxx = rem - dy * 7;
                int g = ((wd * 7 + dz) * DIM + (wh * 7 + dy)) * DIM + (ww * 7 + dxx);
                y[(size_t)g * CH + h * HD + li]      = at0[j] * zq[j];
                y[(size_t)g * CH + h * HD + 16 + li] = at1[j] * zq[j];
            }
        }
    }

    __threadfence_block();   // Phase B y writes visible to conv RMW
    __syncthreads();         // all qfL/kvS reads done before dwcP overwrite

    // ----- Phase C: packed-fp16 depthwise 5x5x5 conv, y += fm + bias ------
    for (int i = tid; i < 16 * 125; i += 256) {
        int cp2 = i / 125, off = i - cp2 * 125;
        unsigned short a = f2h_bits(dwc_w[(2 * cp2) * 125 + off]);
        unsigned short b = f2h_bits(dwc_w[(2 * cp2 + 1) * 125 + off]);
        u.dwcP[i] = (unsigned)a | ((unsigned)b << 16);
    }
    __syncthreads();

    const int cp  = tid & 15;    // channel pair: channels 2cp, 2cp+1
    const int g16 = tid >> 4;    // spatial row group
    const float bias0 = dwc_b[2 * cp], bias1 = dwc_b[2 * cp + 1];

    for (int it = g16; it < 49; it += 16) {
        int dz = it / 7, dy = it - dz * 7;
        h2 fm2[7] = {};
        #pragma unroll
        for (int ka2 = 0; ka2 < 5; ++ka2) {
            int za = dz + ka2 - 2;
            if ((unsigned)za >= 7u) continue;
            #pragma unroll
            for (int kb = 0; kb < 5; ++kb) {
                int zb = dy + kb - 2;
                if ((unsigned)zb >= 7u) continue;
                const unsigned* vb = (const unsigned*)&v16[(za * 49 + zb * 7) * HD + 2 * cp];
                h2 vr[7];
                #pragma unroll
                for (int xx = 0; xx < 7; ++xx)
                    vr[xx] = __builtin_bit_cast(h2, vb[xx * 16]);
                const unsigned* wb = &u.dwcP[cp * 125 + ka2 * 25 + kb * 5];
                h2 w0 = __builtin_bit_cast(h2, wb[0]);
                h2 w1 = __builtin_bit_cast(h2, wb[1]);
                h2 w2 = __builtin_bit_cast(h2, wb[2]);
                h2 w3 = __builtin_bit_cast(h2, wb[3]);
                h2 w4 = __builtin_bit_cast(h2, wb[4]);
                #pragma unroll
                for (int dx2 = 0; dx2 < 7; ++dx2) {
                    if (dx2 - 2 >= 0) fm2[dx2] += vr[dx2 - 2] * w0;
                    if (dx2 - 1 >= 0) fm2[dx2] += vr[dx2 - 1] * w1;
                    fm2[dx2] += vr[dx2] * w2;
                    if (dx2 + 1 <= 6) fm2[dx2] += vr[dx2 + 1] * w3;
                    if (dx2 + 2 <= 6) fm2[dx2] += vr[dx2 + 2] * w4;
                }
            }
        }
        int tokbase = ((wd * 7 + dz) * DIM + (wh * 7 + dy)) * DIM + ww * 7;
        #pragma unroll
        for (int dx2 = 0; dx2 < 7; ++dx2) {
            float* yp = &y[(size_t)(tokbase + dx2) * CH + h * HD + 2 * cp];
            float2 old = *(float2*)yp;
            old.x += (float)fm2[dx2][0] + bias0;
            old.y += (float)fm2[dx2][1] + bias1;
            *(float2*)yp = old;
        }
    }
}

// In-place projection: d_out <- d_out @ w_proj + b_proj. 512 threads
// (2 waves/SIMD latency hiding); each thread 2 tokens x 24 outputs.
__global__ __launch_bounds__(512, 1) void proj_kernel(
    const float* __restrict__ wp, const float* __restrict__ bp,
    float* __restrict__ y)
{
    __shared__ float yt[256 * 97];
    __shared__ float wl[96 * 96];

    const int tid = threadIdx.x;
    const int base = blockIdx.x * 256;

    for (int i = tid; i < 96 * 96; i += 512) wl[i] = wp[i];
    for (int i = tid; i < 256 * 96; i += 512) {
        int r = i / 96; int ch2 = i - r * 96;
        yt[r * 97 + ch2] = y[(base + r) * 96 + ch2];
    }
    __syncthreads();

    const int tokg = tid & 127;
    const int outg = tid >> 7;      // 0..3 -> outputs outg*24..+23

    float acc[2][24];
    #pragma unroll
    for (int jj = 0; jj < 24; ++jj) {
        float b = bp[outg * 24 + jj];
        acc[0][jj] = b; acc[1][jj] = b;
    }

    for (int cc = 0; cc < 96; ++cc) {
        float y0 = yt[(tokg)       * 97 + cc];
        float y1 = yt[(tokg + 128) * 97 + cc];
        const float* wrow = &wl[cc * 96 + outg * 24];
        #pragma unroll
        for (int jj = 0; jj < 24; ++jj) {
            float wvv = wrow[jj];
            acc[0][jj] = fmaf(y0, wvv, acc[0][jj]);
            acc[1][jj] = fmaf(y1, wvv, acc[1][jj]);
        }
    }
    __syncthreads();   // all reads done before in-place writes (same block only)

    #pragma unroll
    for (int i = 0; i < 2; ++i) {
        int tok = base + tokg + 128 * i;
        #pragma unroll
        for (int jj = 0; jj < 24; ++jj)
            y[tok * 96 + outg * 24 + jj] = acc[i][jj];
    }
}

extern "C" void kernel_launch(void* const* d_in, const int* in_sizes, int n_in,
                              void* d_out, int out_size, void* d_ws, size_t ws_size,
                              hipStream_t stream) {
    const float* x           = (const float*)d_in[0];
    const float* w_qkv       = (const float*)d_in[1];
    const float* scale_param = (const float*)d_in[2];
    const float* pos_enc     = (const float*)d_in[3];
    const float* dwc_w       = (const float*)d_in[4];
    const float* dwc_b       = (const float*)d_in[5];
    const float* w_proj      = (const float*)d_in[6];
    const float* b_proj      = (const float*)d_in[7];
    float* out = (float*)d_out;
    unsigned short* wsb = (unsigned short*)d_ws;

    setup_w<<<dim3(216), dim3(256), 0, stream>>>(w_qkv, wsb);
    attn_kernel<<<dim3(NHD * NWIN), dim3(256), 0, stream>>>(
        x, wsb, scale_param, pos_enc, dwc_w, dwc_b, out);
    proj_kernel<<<dim3(686), dim3(512), 0, stream>>>(w_proj, b_proj, out);
}

// Round 23
// 263.729 us; speedup vs baseline: 1.3805x; 1.3805x over previous
//
#include <hip/hip_runtime.h>
#include <math.h>

#define NWIN 512
#define NHD  3
#define NTOK 343
#define HD   32
#define CH   96
#define DIM  56

#define XS 16.0f
#define WS 1024.0f
#define RS (1.0f/16384.0f)   // 2^-14, exact

typedef __attribute__((ext_vector_type(8))) _Float16 f16x8;
typedef __attribute__((ext_vector_type(4))) float f32x4;
typedef __attribute__((ext_vector_type(2))) _Float16 h2;

__device__ __forceinline__ unsigned short f2h_bits(float x) {
    _Float16 h = (_Float16)x;
    return __builtin_bit_cast(unsigned short, h);
}
__device__ __forceinline__ float h2f_bits(unsigned short u) {
    return (float)__builtin_bit_cast(_Float16, u);
}
__device__ __forceinline__ f32x4 mfma16h(f16x8 a, f16x8 b, f32x4 c) {
    return __builtin_amdgcn_mfma_f32_16x16x32_f16(a, b, c, 0, 0, 0);
}
__device__ __forceinline__ float shfl16_sum(float v) {  // sum over lane&15 group
    v += __shfl_xor(v, 1);
    v += __shfl_xor(v, 2);
    v += __shfl_xor(v, 4);
    v += __shfl_xor(v, 8);
    return v;
}

// w_qkv -> split-fp16 MFMA B-fragments in d_ws (110592 B).
// fid = ((((h*3+m)*2+nt)*3+ks)*2+hl); elem = fid*512 + lane*8 + e
__global__ void setup_w(const float* __restrict__ w_qkv,
                        unsigned short* __restrict__ wsb)
{
    int i = blockIdx.x * 256 + threadIdx.x;
    if (i >= 108 * 512) return;
    int e = i & 7, l = (i >> 3) & 63;
    int fid = i >> 9;
    int hl = fid & 1; int f2 = fid >> 1;
    int ks = f2 % 3; int f3 = f2 / 3;
    int nt = f3 & 1; int f4 = f3 >> 1;
    int m  = f4 % 3; int h  = f4 / 3;
    int kg  = ks * 32 + (l >> 4) * 8 + e;
    int col = m * 96 + h * 32 + nt * 16 + (l & 15);
    float w = w_qkv[kg * 288 + col] * WS;
    unsigned short hi = f2h_bits(w);
    wsb[i] = hl ? f2h_bits(w - h2f_bits(hi)) : hi;
}

// Builds scaled fp16-split A-fragments for token (clamped) from global x.
#define BUILD_AFRAG(AH, AL, XPTR)                                           \
  { _Pragma("unroll")                                                       \
    for (int ks = 0; ks < 3; ++ks) {                                        \
        float4 x0 = *(const float4*)((XPTR) + ks * 32);                     \
        float4 x1 = *(const float4*)((XPTR) + ks * 32 + 4);                 \
        union { _Float16 e[8]; f16x8 v; } th, tl;                           \
        float s[8] = {x0.x, x0.y, x0.z, x0.w, x1.x, x1.y, x1.z, x1.w};      \
        _Pragma("unroll")                                                   \
        for (int e = 0; e < 8; ++e) {                                       \
            float sv = s[e] * XS;                                           \
            unsigned short hi = f2h_bits(sv);                               \
            th.e[e] = __builtin_bit_cast(_Float16, hi);                     \
            tl.e[e] = (_Float16)(sv - h2f_bits(hi));                       \
        }                                                                   \
        AH[ks] = th.v; AL[ks] = tl.v;                                       \
    } }

// One block per (head, window), 256 threads, 4 blocks/CU.
// XCD-aware swizzle: swz=(bid&7)*192+(bid>>3); h=swz%3, win=swz/3 -> the 3
// heads of a window are adjacent on one XCD (x becomes L2-hot across heads).
// Phase A/B: proven round-14 structure. Phase C: packed-fp16 conv.
// Union padded to pin LDS at 38912 B (4 blocks/CU) — the 31232B/5-block
// configuration empirically halves throughput (r16/r17); register-qfin
// spills at the 64-VGPR equilibrium (r22). This is a sharp local optimum.
__global__ __launch_bounds__(256, 4) void attn_kernel(
    const float* __restrict__ x, const unsigned short* __restrict__ wsb,
    const float* __restrict__ scale_param, const float* __restrict__ pos_enc,
    const float* __restrict__ dwc_w, const float* __restrict__ dwc_b,
    float* __restrict__ y)
{
    __shared__ __align__(16) unsigned short v16[352 * HD];    // 22528 B
    __shared__ __align__(16) union UU {
        struct PA { unsigned short kf16c[64 * 34]; } pa;      // 4352 B
        struct PB {
            unsigned short qfL[64 * 40];   // 5120 B
            unsigned short kvS[32 * 40];   // 2560 B
            float ksred[4][2][16];         // 512 B
        } pb;                                                 // 8192 B
        unsigned dwcP[16 * 125];                              // 8000 B (packed fp16 pairs)
        float pad_pin_lds[4000];                              // 16000 B -> pins union size
    } u;
    __shared__ float ksum_s[HD];
    __shared__ float sps[HD];
    // total 38784 B (reported 38912) -> 4 blocks/CU

    const int tid = threadIdx.x, bid = blockIdx.x;
    const int swz = (bid & 7) * 192 + (bid >> 3);   // XCD-contiguous id
    const int win = swz / 3;                        // window 0..511
    const int h   = swz - win * 3;                  // head 0..2
    const int wd = win >> 6, wh = (win >> 3) & 7, ww = win & 7;
    const int wv = tid >> 6, lane = tid & 63;
    const int quad = lane >> 4, li = lane & 15;
    const int mtw = wv >> 1, ntw = wv & 1;

    if (tid < HD) {
        float sv = scale_param[tid];
        sps[tid] = (sv > 20.f) ? sv : log1pf(expf(sv));
    }
    __syncthreads();
    const float sp0 = sps[li], sp1 = sps[16 + li];

    const f16x8* wf = (const f16x8*)wsb;
    const int fbase = h * 36;
    float ksp0 = 0.f, ksp1 = 0.f;
    f32x4 kvacc = {0.f, 0.f, 0.f, 0.f};

    // ================= Phase A: k,v over 6 chunks of 64 tokens ===========
    for (int cb0 = 0; cb0 < NTOK; cb0 += 64) {
        const int nj = min(64, NTOK - cb0);
        int atok = cb0 + wv * 16 + li;
        int atc = min(atok, NTOK - 1);
        int adz = atc / 49, arem = atc - adz * 49, ady = arem / 7, adx = arem - ady * 7;
        int gA = ((wd * 7 + adz) * DIM + (wh * 7 + ady)) * DIM + (ww * 7 + adx);
        const float* xr = x + (size_t)gA * CH + quad * 8;
        f16x8 ah[3], al[3];
        BUILD_AFRAG(ah, al, xr);

        f32x4 ak[2] = {{0,0,0,0},{0,0,0,0}};
        f32x4 av[2] = {{0,0,0,0},{0,0,0,0}};
        #pragma unroll
        for (int nt = 0; nt < 2; ++nt) {
            #pragma unroll
            for (int ks = 0; ks < 3; ++ks) {
                int fk = (fbase + ((1 * 2 + nt) * 3 + ks) * 2) * 64 + lane;
                int fv = (fbase + ((2 * 2 + nt) * 3 + ks) * 2) * 64 + lane;
                f16x8 bkh = wf[fk], bkl = wf[fk + 64];
                f16x8 bvh = wf[fv];
                ak[nt] = mfma16h(ah[ks], bkh, ak[nt]);
                ak[nt] = mfma16h(ah[ks], bkl, ak[nt]);
                ak[nt] = mfma16h(al[ks], bkh, ak[nt]);
                av[nt] = mfma16h(ah[ks], bvh, av[nt]);
                av[nt] = mfma16h(al[ks], bvh, av[nt]);
            }
        }

        #pragma unroll
        for (int j = 0; j < 4; ++j) {
            int t16 = quad * 4 + j;
            int tok = cb0 + wv * 16 + t16;
            bool val = tok < NTOK;
            int tc = val ? tok : NTOK - 1;
            float pe0 = pos_enc[tc * HD + li];
            float pe1 = pos_enc[tc * HD + 16 + li];
            float kr0 = ak[0][j] * RS + pe0;
            float kr1 = ak[1][j] * RS + pe1;
            float kp0 = (fmaxf(kr0, 0.f) + 1e-6f) / sp0;
            float kp1 = (fmaxf(kr1, 0.f) + 1e-6f) / sp1;
            float k30 = kp0 * kp0 * kp0, k31 = kp1 * kp1 * kp1;
            float n2k = fmaf(kp0, kp0, kp1 * kp1);
            float n6k = fmaf(k30, k30, k31 * k31);
            n2k = shfl16_sum(n2k); n6k = shfl16_sum(n6k);
            float sk = sqrtf(n2k / n6k);
            float kf0 = k30 * sk, kf1 = k31 * sk;
            int tl = wv * 16 + t16;
            if (val) {
                ksp0 += kf0; ksp1 += kf1;
                u.pa.kf16c[tl * 34 + li]      = f2h_bits(kf0);
                u.pa.kf16c[tl * 34 + 16 + li] = f2h_bits(kf1);
                v16[tok * HD + li]      = f2h_bits(av[0][j] * RS);
                v16[tok * HD + 16 + li] = f2h_bits(av[1][j] * RS);
            } else {
                u.pa.kf16c[tl * 34 + li]      = 0;
                u.pa.kf16c[tl * 34 + 16 + li] = 0;
                if (tok < 352) {
                    v16[tok * HD + li]      = 0;
                    v16[tok * HD + 16 + li] = 0;
                }
            }
        }
        __syncthreads();   // kf16c/v16 ready

        const int nsteps = (nj + 31) >> 5;
        for (int s = 0; s < nsteps; ++s) {
            union { unsigned short u16a[8]; f16x8 v; } a8, b8;
            #pragma unroll
            for (int e = 0; e < 8; ++e) {
                int row = s * 32 + quad * 8 + e;
                a8.u16a[e] = u.pa.kf16c[row * 34 + mtw * 16 + li];
                b8.u16a[e] = v16[(cb0 + row) * HD + ntw * 16 + li];
            }
            kvacc = mfma16h(a8.v, b8.v, kvacc);
        }
        __syncthreads();   // kf16c reads done before next chunk's writes
    }

    // ===== interphase: ksum reduce + kv C-frags -> fp16 kvS B-frag LDS ====
    ksp0 += __shfl_xor(ksp0, 16); ksp0 += __shfl_xor(ksp0, 32);
    ksp1 += __shfl_xor(ksp1, 16); ksp1 += __shfl_xor(ksp1, 32);
    if (quad == 0) { u.pb.ksred[wv][0][li] = ksp0; u.pb.ksred[wv][1][li] = ksp1; }
    #pragma unroll
    for (int j = 0; j < 4; ++j)
        u.pb.kvS[(ntw * 16 + li) * 40 + mtw * 16 + quad * 4 + j] = f2h_bits(kvacc[j]);
    __syncthreads();
    if (tid < HD) {
        ksum_s[tid] = u.pb.ksred[0][tid >> 4][tid & 15] + u.pb.ksred[1][tid >> 4][tid & 15]
                    + u.pb.ksred[2][tid >> 4][tid & 15] + u.pb.ksred[3][tid >> 4][tid & 15];
    }
    __syncthreads();

    // ============ Phase B (barrier-free): q recompute -> z, att -> y ======
    const float ks0 = ksum_s[li], ks1 = ksum_s[16 + li];
    for (int cb0 = 0; cb0 < NTOK; cb0 += 64) {
        int atok = cb0 + wv * 16 + li;
        int atc = min(atok, NTOK - 1);
        int adz = atc / 49, arem = atc - adz * 49, ady = arem / 7, adx = arem - ady * 7;
        int gA = ((wd * 7 + adz) * DIM + (wh * 7 + ady)) * DIM + (ww * 7 + adx);
        const float* xr = x + (size_t)gA * CH + quad * 8;
        f16x8 ah[3], al[3];
        BUILD_AFRAG(ah, al, xr);

        f32x4 aq[2] = {{0,0,0,0},{0,0,0,0}};
        #pragma unroll
        for (int nt = 0; nt < 2; ++nt) {
            #pragma unroll
            for (int ks = 0; ks < 3; ++ks) {
                int fq = (fbase + ((0 * 2 + nt) * 3 + ks) * 2) * 64 + lane;
                f16x8 bqh = wf[fq], bql = wf[fq + 64];
                aq[nt] = mfma16h(ah[ks], bqh, aq[nt]);
                aq[nt] = mfma16h(ah[ks], bql, aq[nt]);
                aq[nt] = mfma16h(al[ks], bqh, aq[nt]);
            }
        }

        float zq[4];
        #pragma unroll
        for (int j = 0; j < 4; ++j) {
            int t16 = quad * 4 + j;
            int tok = cb0 + wv * 16 + t16;
            bool val = tok < NTOK;
            float qp0 = (fmaxf(aq[0][j] * RS, 0.f) + 1e-6f) / sp0;
            float qp1 = (fmaxf(aq[1][j] * RS, 0.f) + 1e-6f) / sp1;
            float q30 = qp0 * qp0 * qp0, q31 = qp1 * qp1 * qp1;
            float n2q = fmaf(qp0, qp0, qp1 * qp1);
            float n6q = fmaf(q30, q30, q31 * q31);
            n2q = shfl16_sum(n2q); n6q = shfl16_sum(n6q);
            float sq = sqrtf(n2q / n6q);
            float qf0 = q30 * sq, qf1 = q31 * sq;
            float zp = shfl16_sum(fmaf(qf0, ks0, qf1 * ks1));
            zq[j] = 1.f / (zp + 1e-6f);
            if (val) {
                int tl = wv * 16 + t16;
                u.pb.qfL[tl * 40 + li]      = f2h_bits(qf0);
                u.pb.qfL[tl * 40 + 16 + li] = f2h_bits(qf1);
            }
        }
        f16x8 aqf = *(const f16x8*)&u.pb.qfL[(wv * 16 + li) * 40 + quad * 8];
        f16x8 bk0 = *(const f16x8*)&u.pb.kvS[li * 40 + quad * 8];
        f16x8 bk1 = *(const f16x8*)&u.pb.kvS[(16 + li) * 40 + quad * 8];
        f32x4 at0 = {0.f, 0.f, 0.f, 0.f}, at1 = {0.f, 0.f, 0.f, 0.f};
        at0 = mfma16h(aqf, bk0, at0);
        at1 = mfma16h(aqf, bk1, at1);

        #pragma unroll
        for (int j = 0; j < 4; ++j) {
            int t16 = quad * 4 + j;
            int tok = cb0 + wv * 16 + t16;
            if (tok < NTOK) {
                int dz = tok / 49, rem = tok - dz * 49, dy = rem / 7, dxx = rem - dy * 7;
                int g = ((wd * 7 + dz) * DIM + (wh * 7 + dy)) * DIM + (ww * 7 + dxx);
                y[(size_t)g * CH + h * HD + li]      = at0[j] * zq[j];
                y[(size_t)g * CH + h * HD + 16 + li] = at1[j] * zq[j];
            }
        }
    }

    __threadfence_block();   // Phase B y writes visible to conv RMW
    __syncthreads();         // all Phase B LDS reads done before dwcP overwrite

    // ----- Phase C: packed-fp16 depthwise 5x5x5 conv, y += fm + bias ------
    for (int i = tid; i < 16 * 125; i += 256) {
        int cp2 = i / 125, off = i - cp2 * 125;
        unsigned short a = f2h_bits(dwc_w[(2 * cp2) * 125 + off]);
        unsigned short b = f2h_bits(dwc_w[(2 * cp2 + 1) * 125 + off]);
        u.dwcP[i] = (unsigned)a | ((unsigned)b << 16);
    }
    __syncthreads();

    const int cp  = tid & 15;    // channel pair: channels 2cp, 2cp+1
    const int g16 = tid >> 4;    // spatial row group
    const float bias0 = dwc_b[2 * cp], bias1 = dwc_b[2 * cp + 1];

    for (int it = g16; it < 49; it += 16) {
        int dz = it / 7, dy = it - dz * 7;
        h2 fm2[7] = {};
        #pragma unroll
        for (int ka2 = 0; ka2 < 5; ++ka2) {
            int za = dz + ka2 - 2;
            if ((unsigned)za >= 7u) continue;
            #pragma unroll
            for (int kb = 0; kb < 5; ++kb) {
                int zb = dy + kb - 2;
                if ((unsigned)zb >= 7u) continue;
                const unsigned* vb = (const unsigned*)&v16[(za * 49 + zb * 7) * HD + 2 * cp];
                h2 vr[7];
                #pragma unroll
                for (int xx = 0; xx < 7; ++xx)
                    vr[xx] = __builtin_bit_cast(h2, vb[xx * 16]);
                const unsigned* wb = &u.dwcP[cp * 125 + ka2 * 25 + kb * 5];
                h2 w0 = __builtin_bit_cast(h2, wb[0]);
                h2 w1 = __builtin_bit_cast(h2, wb[1]);
                h2 w2 = __builtin_bit_cast(h2, wb[2]);
                h2 w3 = __builtin_bit_cast(h2, wb[3]);
                h2 w4 = __builtin_bit_cast(h2, wb[4]);
                #pragma unroll
                for (int dx2 = 0; dx2 < 7; ++dx2) {
                    if (dx2 - 2 >= 0) fm2[dx2] += vr[dx2 - 2] * w0;
                    if (dx2 - 1 >= 0) fm2[dx2] += vr[dx2 - 1] * w1;
                    fm2[dx2] += vr[dx2] * w2;
                    if (dx2 + 1 <= 6) fm2[dx2] += vr[dx2 + 1] * w3;
                    if (dx2 + 2 <= 6) fm2[dx2] += vr[dx2 + 2] * w4;
                }
            }
        }
        int tokbase = ((wd * 7 + dz) * DIM + (wh * 7 + dy)) * DIM + ww * 7;
        #pragma unroll
        for (int dx2 = 0; dx2 < 7; ++dx2) {
            float* yp = &y[(size_t)(tokbase + dx2) * CH + h * HD + 2 * cp];
            float2 old = *(float2*)yp;
            old.x += (float)fm2[dx2][0] + bias0;
            old.y += (float)fm2[dx2][1] + bias1;
            *(float2*)yp = old;
        }
    }
}

// In-place projection: d_out <- d_out @ w_proj + b_proj. 512 threads
// (2 waves/SIMD latency hiding); each thread 2 tokens x 24 outputs.
// (round-14/18 proven version)
__global__ __launch_bounds__(512, 1) void proj_kernel(
    const float* __restrict__ wp, const float* __restrict__ bp,
    float* __restrict__ y)
{
    __shared__ float yt[256 * 97];
    __shared__ float wl[96 * 96];

    const int tid = threadIdx.x;
    const int base = blockIdx.x * 256;

    for (int i = tid; i < 96 * 96; i += 512) wl[i] = wp[i];
    for (int i = tid; i < 256 * 96; i += 512) {
        int r = i / 96; int ch2 = i - r * 96;
        yt[r * 97 + ch2] = y[(base + r) * 96 + ch2];
    }
    __syncthreads();

    const int tokg = tid & 127;
    const int outg = tid >> 7;      // 0..3 -> outputs outg*24..+23

    float acc[2][24];
    #pragma unroll
    for (int jj = 0; jj < 24; ++jj) {
        float b = bp[outg * 24 + jj];
        acc[0][jj] = b; acc[1][jj] = b;
    }

    for (int cc = 0; cc < 96; ++cc) {
        float y0 = yt[(tokg)       * 97 + cc];
        float y1 = yt[(tokg + 128) * 97 + cc];
        const float* wrow = &wl[cc * 96 + outg * 24];
        #pragma unroll
        for (int jj = 0; jj < 24; ++jj) {
            float wvv = wrow[jj];
            acc[0][jj] = fmaf(y0, wvv, acc[0][jj]);
            acc[1][jj] = fmaf(y1, wvv, acc[1][jj]);
        }
    }
    __syncthreads();   // all reads done before in-place writes (same block only)

    #pragma unroll
    for (int i = 0; i < 2; ++i) {
        int tok = base + tokg + 128 * i;
        #pragma unroll
        for (int jj = 0; jj < 24; ++jj)
            y[tok * 96 + outg * 24 + jj] = acc[i][jj];
    }
}

extern "C" void kernel_launch(void* const* d_in, const int* in_sizes, int n_in,
                              void* d_out, int out_size, void* d_ws, size_t ws_size,
                              hipStream_t stream) {
    const float* x           = (const float*)d_in[0];
    const float* w_qkv       = (const float*)d_in[1];
    const float* scale_param = (const float*)d_in[2];
    const float* pos_enc     = (const float*)d_in[3];
    const float* dwc_w       = (const float*)d_in[4];
    const float* dwc_b       = (const float*)d_in[5];
    const float* w_proj      = (const float*)d_in[6];
    const float* b_proj      = (const float*)d_in[7];
    float* out = (float*)d_out;
    unsigned short* wsb = (unsigned short*)d_ws;

    setup_w<<<dim3(216), dim3(256), 0, stream>>>(w_qkv, wsb);
    attn_kernel<<<dim3(NHD * NWIN), dim3(256), 0, stream>>>(
        x, wsb, scale_param, pos_enc, dwc_w, dwc_b, out);
    proj_kernel<<<dim3(686), dim3(512), 0, stream>>>(w_proj, b_proj, out);
}

// Round 24
// 260.893 us; speedup vs baseline: 1.3955x; 1.0109x over previous
//
#include <hip/hip_runtime.h>
#include <math.h>

#define NWIN 512
#define NHD  3
#define NTOK 343
#define HD   32
#define CH   96
#define DIM  56

#define XS 16.0f
#define WS 1024.0f
#define RS (1.0f/16384.0f)   // 2^-14, exact

typedef __attribute__((ext_vector_type(8))) _Float16 f16x8;
typedef __attribute__((ext_vector_type(4))) float f32x4;
typedef __attribute__((ext_vector_type(2))) _Float16 h2;

__device__ __forceinline__ unsigned short f2h_bits(float x) {
    _Float16 h = (_Float16)x;
    return __builtin_bit_cast(unsigned short, h);
}
__device__ __forceinline__ float h2f_bits(unsigned short u) {
    return (float)__builtin_bit_cast(_Float16, u);
}
__device__ __forceinline__ f32x4 mfma16h(f16x8 a, f16x8 b, f32x4 c) {
    return __builtin_amdgcn_mfma_f32_16x16x32_f16(a, b, c, 0, 0, 0);
}
__device__ __forceinline__ float shfl16_sum(float v) {  // sum over lane&15 group
    v += __shfl_xor(v, 1);
    v += __shfl_xor(v, 2);
    v += __shfl_xor(v, 4);
    v += __shfl_xor(v, 8);
    return v;
}

// w_qkv -> split-fp16 MFMA B-fragments in d_ws (110592 B).
// fid = ((((h*3+m)*2+nt)*3+ks)*2+hl); elem = fid*512 + lane*8 + e
__global__ void setup_w(const float* __restrict__ w_qkv,
                        unsigned short* __restrict__ wsb)
{
    int i = blockIdx.x * 256 + threadIdx.x;
    if (i >= 108 * 512) return;
    int e = i & 7, l = (i >> 3) & 63;
    int fid = i >> 9;
    int hl = fid & 1; int f2 = fid >> 1;
    int ks = f2 % 3; int f3 = f2 / 3;
    int nt = f3 & 1; int f4 = f3 >> 1;
    int m  = f4 % 3; int h  = f4 / 3;
    int kg  = ks * 32 + (l >> 4) * 8 + e;
    int col = m * 96 + h * 32 + nt * 16 + (l & 15);
    float w = w_qkv[kg * 288 + col] * WS;
    unsigned short hi = f2h_bits(w);
    wsb[i] = hl ? f2h_bits(w - h2f_bits(hi)) : hi;
}

// Builds scaled fp16-split A-fragments for token (clamped) from global x.
#define BUILD_AFRAG(AH, AL, XPTR)                                           \
  { _Pragma("unroll")                                                       \
    for (int ks = 0; ks < 3; ++ks) {                                        \
        float4 x0 = *(const float4*)((XPTR) + ks * 32);                     \
        float4 x1 = *(const float4*)((XPTR) + ks * 32 + 4);                 \
        union { _Float16 e[8]; f16x8 v; } th, tl;                           \
        float s[8] = {x0.x, x0.y, x0.z, x0.w, x1.x, x1.y, x1.z, x1.w};      \
        _Pragma("unroll")                                                   \
        for (int e = 0; e < 8; ++e) {                                       \
            float sv = s[e] * XS;                                           \
            unsigned short hi = f2h_bits(sv);                               \
            th.e[e] = __builtin_bit_cast(_Float16, hi);                     \
            tl.e[e] = (_Float16)(sv - h2f_bits(hi));                       \
        }                                                                   \
        AH[ks] = th.v; AL[ks] = tl.v;                                       \
    } }

// One block per (head, window), 256 threads, 4 blocks/CU.
// XCD-aware swizzle: swz=(bid&7)*192+(bid>>3); h=swz%3, win=swz/3.
// Phase A/B: proven round-14 structure + T5 setprio around MFMA clusters.
// Phase C: packed-fp16 conv. Union padded to pin LDS at 38912 B (4 blocks/CU)
// — the 31232B/5-block config empirically halves throughput (r16/r17);
// register-qfin spills at the 64-VGPR equilibrium (r22). Sharp local optimum.
__global__ __launch_bounds__(256, 4) void attn_kernel(
    const float* __restrict__ x, const unsigned short* __restrict__ wsb,
    const float* __restrict__ scale_param, const float* __restrict__ pos_enc,
    const float* __restrict__ dwc_w, const float* __restrict__ dwc_b,
    float* __restrict__ y)
{
    __shared__ __align__(16) unsigned short v16[352 * HD];    // 22528 B
    __shared__ __align__(16) union UU {
        struct PA { unsigned short kf16c[64 * 34]; } pa;      // 4352 B
        struct PB {
            unsigned short qfL[64 * 40];   // 5120 B
            unsigned short kvS[32 * 40];   // 2560 B
            float ksred[4][2][16];         // 512 B
        } pb;                                                 // 8192 B
        unsigned dwcP[16 * 125];                              // 8000 B (packed fp16 pairs)
        float pad_pin_lds[4000];                              // 16000 B -> pins union size
    } u;
    __shared__ float ksum_s[HD];
    __shared__ float sps[HD];
    // total 38784 B (reported 38912) -> 4 blocks/CU

    const int tid = threadIdx.x, bid = blockIdx.x;
    const int swz = (bid & 7) * 192 + (bid >> 3);   // XCD-contiguous id
    const int win = swz / 3;                        // window 0..511
    const int h   = swz - win * 3;                  // head 0..2
    const int wd = win >> 6, wh = (win >> 3) & 7, ww = win & 7;
    const int wv = tid >> 6, lane = tid & 63;
    const int quad = lane >> 4, li = lane & 15;
    const int mtw = wv >> 1, ntw = wv & 1;

    if (tid < HD) {
        float sv = scale_param[tid];
        sps[tid] = (sv > 20.f) ? sv : log1pf(expf(sv));
    }
    __syncthreads();
    const float sp0 = sps[li], sp1 = sps[16 + li];

    const f16x8* wf = (const f16x8*)wsb;
    const int fbase = h * 36;
    float ksp0 = 0.f, ksp1 = 0.f;
    f32x4 kvacc = {0.f, 0.f, 0.f, 0.f};

    // ================= Phase A: k,v over 6 chunks of 64 tokens ===========
    for (int cb0 = 0; cb0 < NTOK; cb0 += 64) {
        const int nj = min(64, NTOK - cb0);
        int atok = cb0 + wv * 16 + li;
        int atc = min(atok, NTOK - 1);
        int adz = atc / 49, arem = atc - adz * 49, ady = arem / 7, adx = arem - ady * 7;
        int gA = ((wd * 7 + adz) * DIM + (wh * 7 + ady)) * DIM + (ww * 7 + adx);
        const float* xr = x + (size_t)gA * CH + quad * 8;
        f16x8 ah[3], al[3];
        BUILD_AFRAG(ah, al, xr);

        f32x4 ak[2] = {{0,0,0,0},{0,0,0,0}};
        f32x4 av[2] = {{0,0,0,0},{0,0,0,0}};
        __builtin_amdgcn_s_setprio(1);           // T5: favor MFMA cluster
        #pragma unroll
        for (int nt = 0; nt < 2; ++nt) {
            #pragma unroll
            for (int ks = 0; ks < 3; ++ks) {
                int fk = (fbase + ((1 * 2 + nt) * 3 + ks) * 2) * 64 + lane;
                int fv = (fbase + ((2 * 2 + nt) * 3 + ks) * 2) * 64 + lane;
                f16x8 bkh = wf[fk], bkl = wf[fk + 64];
                f16x8 bvh = wf[fv];
                ak[nt] = mfma16h(ah[ks], bkh, ak[nt]);
                ak[nt] = mfma16h(ah[ks], bkl, ak[nt]);
                ak[nt] = mfma16h(al[ks], bkh, ak[nt]);
                av[nt] = mfma16h(ah[ks], bvh, av[nt]);
                av[nt] = mfma16h(al[ks], bvh, av[nt]);
            }
        }
        __builtin_amdgcn_s_setprio(0);

        #pragma unroll
        for (int j = 0; j < 4; ++j) {
            int t16 = quad * 4 + j;
            int tok = cb0 + wv * 16 + t16;
            bool val = tok < NTOK;
            int tc = val ? tok : NTOK - 1;
            float pe0 = pos_enc[tc * HD + li];
            float pe1 = pos_enc[tc * HD + 16 + li];
            float kr0 = ak[0][j] * RS + pe0;
            float kr1 = ak[1][j] * RS + pe1;
            float kp0 = (fmaxf(kr0, 0.f) + 1e-6f) / sp0;
            float kp1 = (fmaxf(kr1, 0.f) + 1e-6f) / sp1;
            float k30 = kp0 * kp0 * kp0, k31 = kp1 * kp1 * kp1;
            float n2k = fmaf(kp0, kp0, kp1 * kp1);
            float n6k = fmaf(k30, k30, k31 * k31);
            n2k = shfl16_sum(n2k); n6k = shfl16_sum(n6k);
            float sk = sqrtf(n2k / n6k);
            float kf0 = k30 * sk, kf1 = k31 * sk;
            int tl = wv * 16 + t16;
            if (val) {
                ksp0 += kf0; ksp1 += kf1;
                u.pa.kf16c[tl * 34 + li]      = f2h_bits(kf0);
                u.pa.kf16c[tl * 34 + 16 + li] = f2h_bits(kf1);
                v16[tok * HD + li]      = f2h_bits(av[0][j] * RS);
                v16[tok * HD + 16 + li] = f2h_bits(av[1][j] * RS);
            } else {
                u.pa.kf16c[tl * 34 + li]      = 0;
                u.pa.kf16c[tl * 34 + 16 + li] = 0;
                if (tok < 352) {
                    v16[tok * HD + li]      = 0;
                    v16[tok * HD + 16 + li] = 0;
                }
            }
        }
        __syncthreads();   // kf16c/v16 ready

        const int nsteps = (nj + 31) >> 5;
        for (int s = 0; s < nsteps; ++s) {
            union { unsigned short u16a[8]; f16x8 v; } a8, b8;
            #pragma unroll
            for (int e = 0; e < 8; ++e) {
                int row = s * 32 + quad * 8 + e;
                a8.u16a[e] = u.pa.kf16c[row * 34 + mtw * 16 + li];
                b8.u16a[e] = v16[(cb0 + row) * HD + ntw * 16 + li];
            }
            kvacc = mfma16h(a8.v, b8.v, kvacc);
        }
        __syncthreads();   // kf16c reads done before next chunk's writes
    }

    // ===== interphase: ksum reduce + kv C-frags -> fp16 kvS B-frag LDS ====
    ksp0 += __shfl_xor(ksp0, 16); ksp0 += __shfl_xor(ksp0, 32);
    ksp1 += __shfl_xor(ksp1, 16); ksp1 += __shfl_xor(ksp1, 32);
    if (quad == 0) { u.pb.ksred[wv][0][li] = ksp0; u.pb.ksred[wv][1][li] = ksp1; }
    #pragma unroll
    for (int j = 0; j < 4; ++j)
        u.pb.kvS[(ntw * 16 + li) * 40 + mtw * 16 + quad * 4 + j] = f2h_bits(kvacc[j]);
    __syncthreads();
    if (tid < HD) {
        ksum_s[tid] = u.pb.ksred[0][tid >> 4][tid & 15] + u.pb.ksred[1][tid >> 4][tid & 15]
                    + u.pb.ksred[2][tid >> 4][tid & 15] + u.pb.ksred[3][tid >> 4][tid & 15];
    }
    __syncthreads();

    // ============ Phase B (barrier-free): q recompute -> z, att -> y ======
    const float ks0 = ksum_s[li], ks1 = ksum_s[16 + li];
    for (int cb0 = 0; cb0 < NTOK; cb0 += 64) {
        int atok = cb0 + wv * 16 + li;
        int atc = min(atok, NTOK - 1);
        int adz = atc / 49, arem = atc - adz * 49, ady = arem / 7, adx = arem - ady * 7;
        int gA = ((wd * 7 + adz) * DIM + (wh * 7 + ady)) * DIM + (ww * 7 + adx);
        const float* xr = x + (size_t)gA * CH + quad * 8;
        f16x8 ah[3], al[3];
        BUILD_AFRAG(ah, al, xr);

        f32x4 aq[2] = {{0,0,0,0},{0,0,0,0}};
        __builtin_amdgcn_s_setprio(1);           // T5: favor MFMA cluster
        #pragma unroll
        for (int nt = 0; nt < 2; ++nt) {
            #pragma unroll
            for (int ks = 0; ks < 3; ++ks) {
                int fq = (fbase + ((0 * 2 + nt) * 3 + ks) * 2) * 64 + lane;
                f16x8 bqh = wf[fq], bql = wf[fq + 64];
                aq[nt] = mfma16h(ah[ks], bqh, aq[nt]);
                aq[nt] = mfma16h(ah[ks], bql, aq[nt]);
                aq[nt] = mfma16h(al[ks], bqh, aq[nt]);
            }
        }
        __builtin_amdgcn_s_setprio(0);

        float zq[4];
        #pragma unroll
        for (int j = 0; j < 4; ++j) {
            int t16 = quad * 4 + j;
            int tok = cb0 + wv * 16 + t16;
            bool val = tok < NTOK;
            float qp0 = (fmaxf(aq[0][j] * RS, 0.f) + 1e-6f) / sp0;
            float qp1 = (fmaxf(aq[1][j] * RS, 0.f) + 1e-6f) / sp1;
            float q30 = qp0 * qp0 * qp0, q31 = qp1 * qp1 * qp1;
            float n2q = fmaf(qp0, qp0, qp1 * qp1);
            float n6q = fmaf(q30, q30, q31 * q31);
            n2q = shfl16_sum(n2q); n6q = shfl16_sum(n6q);
            float sq = sqrtf(n2q / n6q);
            float qf0 = q30 * sq, qf1 = q31 * sq;
            float zp = shfl16_sum(fmaf(qf0, ks0, qf1 * ks1));
            zq[j] = 1.f / (zp + 1e-6f);
            if (val) {
                int tl = wv * 16 + t16;
                u.pb.qfL[tl * 40 + li]      = f2h_bits(qf0);
                u.pb.qfL[tl * 40 + 16 + li] = f2h_bits(qf1);
            }
        }
        f16x8 aqf = *(const f16x8*)&u.pb.qfL[(wv * 16 + li) * 40 + quad * 8];
        f16x8 bk0 = *(const f16x8*)&u.pb.kvS[li * 40 + quad * 8];
        f16x8 bk1 = *(const f16x8*)&u.pb.kvS[(16 + li) * 40 + quad * 8];
        f32x4 at0 = {0.f, 0.f, 0.f, 0.f}, at1 = {0.f, 0.f, 0.f, 0.f};
        at0 = mfma16h(aqf, bk0, at0);
        at1 = mfma16h(aqf, bk1, at1);

        #pragma unroll
        for (int j = 0; j < 4; ++j) {
            int t16 = quad * 4 + j;
            int tok = cb0 + wv * 16 + t16;
            if (tok < NTOK) {
                int dz = tok / 49, rem = tok - dz * 49, dy = rem / 7, dxx = rem - dy * 7;
                int g = ((wd * 7 + dz) * DIM + (wh * 7 + dy)) * DIM + (ww * 7 + dxx);
                y[(size_t)g * CH + h * HD + li]      = at0[j] * zq[j];
                y[(size_t)g * CH + h * HD + 16 + li] = at1[j] * zq[j];
            }
        }
    }

    __threadfence_block();   // Phase B y writes visible to conv RMW
    __syncthreads();         // all Phase B LDS reads done before dwcP overwrite

    // ----- Phase C: packed-fp16 depthwise 5x5x5 conv, y += fm + bias ------
    for (int i = tid; i < 16 * 125; i += 256) {
        int cp2 = i / 125, off = i - cp2 * 125;
        unsigned short a = f2h_bits(dwc_w[(2 * cp2) * 125 + off]);
        unsigned short b = f2h_bits(dwc_w[(2 * cp2 + 1) * 125 + off]);
        u.dwcP[i] = (unsigned)a | ((unsigned)b << 16);
    }
    __syncthreads();

    const int cp  = tid & 15;    // channel pair: channels 2cp, 2cp+1
    const int g16 = tid >> 4;    // spatial row group
    const float bias0 = dwc_b[2 * cp], bias1 = dwc_b[2 * cp + 1];

    for (int it = g16; it < 49; it += 16) {
        int dz = it / 7, dy = it - dz * 7;
        h2 fm2[7] = {};
        #pragma unroll
        for (int ka2 = 0; ka2 < 5; ++ka2) {
            int za = dz + ka2 - 2;
            if ((unsigned)za >= 7u) continue;
            #pragma unroll
            for (int kb = 0; kb < 5; ++kb) {
                int zb = dy + kb - 2;
                if ((unsigned)zb >= 7u) continue;
                const unsigned* vb = (const unsigned*)&v16[(za * 49 + zb * 7) * HD + 2 * cp];
                h2 vr[7];
                #pragma unroll
                for (int xx = 0; xx < 7; ++xx)
                    vr[xx] = __builtin_bit_cast(h2, vb[xx * 16]);
                const unsigned* wb = &u.dwcP[cp * 125 + ka2 * 25 + kb * 5];
                h2 w0 = __builtin_bit_cast(h2, wb[0]);
                h2 w1 = __builtin_bit_cast(h2, wb[1]);
                h2 w2 = __builtin_bit_cast(h2, wb[2]);
                h2 w3 = __builtin_bit_cast(h2, wb[3]);
                h2 w4 = __builtin_bit_cast(h2, wb[4]);
                #pragma unroll
                for (int dx2 = 0; dx2 < 7; ++dx2) {
                    if (dx2 - 2 >= 0) fm2[dx2] += vr[dx2 - 2] * w0;
                    if (dx2 - 1 >= 0) fm2[dx2] += vr[dx2 - 1] * w1;
                    fm2[dx2] += vr[dx2] * w2;
                    if (dx2 + 1 <= 6) fm2[dx2] += vr[dx2 + 1] * w3;
                    if (dx2 + 2 <= 6) fm2[dx2] += vr[dx2 + 2] * w4;
                }
            }
        }
        int tokbase = ((wd * 7 + dz) * DIM + (wh * 7 + dy)) * DIM + ww * 7;
        #pragma unroll
        for (int dx2 = 0; dx2 < 7; ++dx2) {
            float* yp = &y[(size_t)(tokbase + dx2) * CH + h * HD + 2 * cp];
            float2 old = *(float2*)yp;
            old.x += (float)fm2[dx2][0] + bias0;
            old.y += (float)fm2[dx2][1] + bias1;
            *(float2*)yp = old;
        }
    }
}

// In-place projection: d_out <- d_out @ w_proj + b_proj. 512 threads
// (2 waves/SIMD latency hiding); each thread 2 tokens x 24 outputs.
// (round-14/18 proven version)
__global__ __launch_bounds__(512, 1) void proj_kernel(
    const float* __restrict__ wp, const float* __restrict__ bp,
    float* __restrict__ y)
{
    __shared__ float yt[256 * 97];
    __shared__ float wl[96 * 96];

    const int tid = threadIdx.x;
    const int base = blockIdx.x * 256;

    for (int i = tid; i < 96 * 96; i += 512) wl[i] = wp[i];
    for (int i = tid; i < 256 * 96; i += 512) {
        int r = i / 96; int ch2 = i - r * 96;
        yt[r * 97 + ch2] = y[(base + r) * 96 + ch2];
    }
    __syncthreads();

    const int tokg = tid & 127;
    const int outg = tid >> 7;      // 0..3 -> outputs outg*24..+23

    float acc[2][24];
    #pragma unroll
    for (int jj = 0; jj < 24; ++jj) {
        float b = bp[outg * 24 + jj];
        acc[0][jj] = b; acc[1][jj] = b;
    }

    for (int cc = 0; cc < 96; ++cc) {
        float y0 = yt[(tokg)       * 97 + cc];
        float y1 = yt[(tokg + 128) * 97 + cc];
        const float* wrow = &wl[cc * 96 + outg * 24];
        #pragma unroll
        for (int jj = 0; jj < 24; ++jj) {
            float wvv = wrow[jj];
            acc[0][jj] = fmaf(y0, wvv, acc[0][jj]);
            acc[1][jj] = fmaf(y1, wvv, acc[1][jj]);
        }
    }
    __syncthreads();   // all reads done before in-place writes (same block only)

    #pragma unroll
    for (int i = 0; i < 2; ++i) {
        int tok = base + tokg + 128 * i;
        #pragma unroll
        for (int jj = 0; jj < 24; ++jj)
            y[tok * 96 + outg * 24 + jj] = acc[i][jj];
    }
}

extern "C" void kernel_launch(void* const* d_in, const int* in_sizes, int n_in,
                              void* d_out, int out_size, void* d_ws, size_t ws_size,
                              hipStream_t stream) {
    const float* x           = (const float*)d_in[0];
    const float* w_qkv       = (const float*)d_in[1];
    const float* scale_param = (const float*)d_in[2];
    const float* pos_enc     = (const float*)d_in[3];
    const float* dwc_w       = (const float*)d_in[4];
    const float* dwc_b       = (const float*)d_in[5];
    const float* w_proj      = (const float*)d_in[6];
    const float* b_proj      = (const float*)d_in[7];
    float* out = (float*)d_out;
    unsigned short* wsb = (unsigned short*)d_ws;

    setup_w<<<dim3(216), dim3(256), 0, stream>>>(w_qkv, wsb);
    attn_kernel<<<dim3(NHD * NWIN), dim3(256), 0, stream>>>(
        x, wsb, scale_param, pos_enc, dwc_w, dwc_b, out);
    proj_kernel<<<dim3(686), dim3(512), 0, stream>>>(w_proj, b_proj, out);
}